// Round 3
// baseline (261.757 us; speedup 1.0000x reference)
//
#include <hip/hip_runtime.h>
#include <hip/hip_bf16.h>

// Linear layer: out[M,N] = x[M,K] @ W[N,K]^T + b[N], fp32 in/out.
// M=32768, N=512, K=512.
// R3: barrier-free. Both A and W are K-contiguous, which IS the MFMA
// fragment layout -> load frags directly global->reg, cvt fp32->bf16,
// MFMA. No LDS, no __syncthreads; waves fully independent and
// software-pipelined by the compiler. XCD swizzle keeps A-tile sharers
// on one XCD's L2.

#define M_DIM 32768
#define N_DIM 512
#define K_DIM 512

typedef __bf16 bf16x8 __attribute__((ext_vector_type(8)));
typedef float floatx4 __attribute__((ext_vector_type(4)));

__global__ __launch_bounds__(256, 2) void linear_bf16_direct(
    const float* __restrict__ A,    // [M, K]
    const float* __restrict__ W,    // [N, K]
    const float* __restrict__ bias, // [N]
    float* __restrict__ C)          // [M, N]
{
    const int t = threadIdx.x;
    const int wave = t >> 6;
    const int lane = t & 63;
    const int l16 = lane & 15;
    const int kh = lane >> 4;      // quad: which 8-elem K chunk of the frag

    // Swizzle: bid = slot*8 + xcd (runtime maps bid%8 -> XCD round-robin).
    // Each XCD gets a contiguous m-range; the 4 n-tiles of an m-tile are
    // consecutive slots on ONE XCD -> A-tile served from that XCD's L2.
    const int bid = blockIdx.x;
    const int xcd = bid & 7;
    const int slot = bid >> 3;
    const int nT = slot & 3;         // N/128 = 4
    const int mT = xcd * 32 + (slot >> 2);   // M/128 = 256
    // Wave tile: 2x2 waves of 64x64. Waves sharing a row-slab (A) or
    // col-slab (W) hit the same cache lines -> L1/L2 reuse.
    const int mBase = mT * 128 + (wave >> 1) * 64;
    const int nBase = nT * 128 + (wave & 1) * 64;

    // Per-lane fragment row pointers (K-contiguous).
    const float* aP[4];
    const float* wP[4];
#pragma unroll
    for (int i = 0; i < 4; ++i) {
        aP[i] = A + (size_t)(mBase + i * 16 + l16) * K_DIM + kh * 8;
        wP[i] = W + (size_t)(nBase + i * 16 + l16) * K_DIM + kh * 8;
    }

    floatx4 acc[4][4];
#pragma unroll
    for (int i = 0; i < 4; ++i)
#pragma unroll
        for (int j = 0; j < 4; ++j)
            acc[i][j] = (floatx4)0.f;

#pragma unroll 4
    for (int kt = 0; kt < K_DIM; kt += 32) {
        bf16x8 aF[4], wF[4];
#pragma unroll
        for (int i = 0; i < 4; ++i) {
            floatx4 a0 = *(const floatx4*)(aP[i] + kt);
            floatx4 a1 = *(const floatx4*)(aP[i] + kt + 4);
            floatx4 w0 = *(const floatx4*)(wP[i] + kt);
            floatx4 w1 = *(const floatx4*)(wP[i] + kt + 4);
#pragma unroll
            for (int j = 0; j < 4; ++j) {
                aF[i][j]     = (__bf16)a0[j];
                aF[i][4 + j] = (__bf16)a1[j];
                wF[i][j]     = (__bf16)w0[j];
                wF[i][4 + j] = (__bf16)w1[j];
            }
        }
#pragma unroll
        for (int mi = 0; mi < 4; ++mi)
#pragma unroll
            for (int ni = 0; ni < 4; ++ni)
                acc[mi][ni] = __builtin_amdgcn_mfma_f32_16x16x32_bf16(
                    aF[mi], wF[ni], acc[mi][ni], 0, 0, 0);
    }

    // Epilogue: D mapping col = lane&15, row = (lane>>4)*4 + reg (verified).
#pragma unroll
    for (int ni = 0; ni < 4; ++ni) {
        const int gcol = nBase + ni * 16 + l16;
        const float bv = bias[gcol];
#pragma unroll
        for (int mi = 0; mi < 4; ++mi) {
            const int rowBase = mBase + mi * 16 + kh * 4;
#pragma unroll
            for (int r = 0; r < 4; ++r)
                C[(size_t)(rowBase + r) * N_DIM + gcol] = acc[mi][ni][r] + bv;
        }
    }
}

extern "C" void kernel_launch(void* const* d_in, const int* in_sizes, int n_in,
                              void* d_out, int out_size, void* d_ws, size_t ws_size,
                              hipStream_t stream) {
    const float* x = (const float*)d_in[0];
    const float* w = (const float*)d_in[1];
    const float* b = (const float*)d_in[2];
    float* out = (float*)d_out;

    dim3 grid((M_DIM / 128) * (N_DIM / 128));  // 1024 blocks, 1D for swizzle
    dim3 block(256);
    linear_bf16_direct<<<grid, block, 0, stream>>>(x, w, b, out);
}

// Round 4
// 201.392 us; speedup vs baseline: 1.2997x; 1.2997x over previous
//
#include <hip/hip_runtime.h>
#include <hip/hip_bf16.h>

// Linear layer: out[M,N] = x[M,K] @ W[N,K]^T + b[N], fp32 in/out.
// M=32768, N=512, K=512.
// R4: single-wave workgroups (64 thr) computing 64x64 tiles.
//  - __syncthreads in a 1-wave block elides s_barrier -> no wave coupling;
//    each wave pipelines its own K-loop independently.
//  - 4096 blocks = 16 blocks/CU (vs 4 in R2) -> TLP fills latency gaps.
//  - LDS row stride 36 bf16 (18 dwords, gcd(18,32)=2) -> 2-way max bank
//    aliasing (free), vs R2's stride 40 (gcd 4 -> measured 4.2M conflict cyc).
//  - XCD swizzle: 8 n-tiles of an m-tile adjacent on one XCD (A L2 reuse).

#define M_DIM 32768
#define N_DIM 512
#define K_DIM 512
#define BK 32
#define LDW 36   // LDS row stride in bf16 elems

typedef __bf16 bf16x8 __attribute__((ext_vector_type(8)));
typedef float floatx4 __attribute__((ext_vector_type(4)));

__global__ __launch_bounds__(64, 3) void linear_wave_tile(
    const float* __restrict__ A,    // [M, K]
    const float* __restrict__ W,    // [N, K]
    const float* __restrict__ bias, // [N]
    float* __restrict__ C)          // [M, N]
{
    __shared__ __bf16 sA[64 * LDW];
    __shared__ __bf16 sW[64 * LDW];

    const int t = threadIdx.x;          // == lane, single wave
    const int l16 = t & 15;
    const int kh = t >> 4;              // 0..3

    // Swizzle: bid = slot*8 + xcd. Consecutive slots on one XCD cover the
    // 8 n-tiles of one m-tile -> A-tile (128KB) reused from that XCD's L2.
    const int bid = blockIdx.x;
    const int xcd = bid & 7;
    const int slot = bid >> 3;          // 0..511
    const int nT = slot & 7;            // N/64 = 8
    const int mT = xcd * 64 + (slot >> 3);  // M/64 = 512
    const int mBase = mT * 64;
    const int nBase = nT * 64;

    // Staging: 64x32 fp32 tile; lane covers row = (t>>2) + i*16, 8 floats at
    // col (t&3)*8. 4 lanes/row x 32B = 128B contiguous per row -> coalesced.
    const int sRow = t >> 2;            // 0..15
    const int sCol = (t & 3) * 8;       // 0,8,16,24
    const float* aBase = A + (size_t)(mBase + sRow) * K_DIM + sCol;
    const float* wBase = W + (size_t)(nBase + sRow) * K_DIM + sCol;

    floatx4 acc[4][4];
#pragma unroll
    for (int i = 0; i < 4; ++i)
#pragma unroll
        for (int j = 0; j < 4; ++j)
            acc[i][j] = (floatx4)0.f;

#pragma unroll 2
    for (int kt = 0; kt < K_DIM; kt += BK) {
        __syncthreads();  // 1-wave block: compiles to waitcnt only (no s_barrier)
#pragma unroll
        for (int i = 0; i < 4; ++i) {
            const int row = sRow + i * 16;
            const float* ap = aBase + kt + (size_t)i * 16 * K_DIM;
            const float* wp = wBase + kt + (size_t)i * 16 * K_DIM;
            floatx4 a0 = *(const floatx4*)ap;
            floatx4 a1 = *(const floatx4*)(ap + 4);
            floatx4 w0 = *(const floatx4*)wp;
            floatx4 w1 = *(const floatx4*)(wp + 4);
            bf16x8 av, wv;
#pragma unroll
            for (int j = 0; j < 4; ++j) {
                av[j]     = (__bf16)a0[j];
                av[4 + j] = (__bf16)a1[j];
                wv[j]     = (__bf16)w0[j];
                wv[4 + j] = (__bf16)w1[j];
            }
            *(bf16x8*)&sA[row * LDW + sCol] = av;
            *(bf16x8*)&sW[row * LDW + sCol] = wv;
        }
        __syncthreads();  // waitcnt only

        bf16x8 aF[4], wF[4];
#pragma unroll
        for (int i = 0; i < 4; ++i) {
            aF[i] = *(const bf16x8*)&sA[(i * 16 + l16) * LDW + kh * 8];
            wF[i] = *(const bf16x8*)&sW[(i * 16 + l16) * LDW + kh * 8];
        }

#pragma unroll
        for (int mi = 0; mi < 4; ++mi)
#pragma unroll
            for (int ni = 0; ni < 4; ++ni)
                acc[mi][ni] = __builtin_amdgcn_mfma_f32_16x16x32_bf16(
                    aF[mi], wF[ni], acc[mi][ni], 0, 0, 0);
    }

    // Epilogue: D mapping col = lane&15, row = (lane>>4)*4 + reg (verified).
#pragma unroll
    for (int ni = 0; ni < 4; ++ni) {
        const int gcol = nBase + ni * 16 + l16;
        const float bv = bias[gcol];
#pragma unroll
        for (int mi = 0; mi < 4; ++mi) {
            const int rowBase = mBase + mi * 16 + kh * 4;
#pragma unroll
            for (int r = 0; r < 4; ++r)
                C[(size_t)(rowBase + r) * N_DIM + gcol] = acc[mi][ni][r] + bv;
        }
    }
}

extern "C" void kernel_launch(void* const* d_in, const int* in_sizes, int n_in,
                              void* d_out, int out_size, void* d_ws, size_t ws_size,
                              hipStream_t stream) {
    const float* x = (const float*)d_in[0];
    const float* w = (const float*)d_in[1];
    const float* b = (const float*)d_in[2];
    float* out = (float*)d_out;

    dim3 grid((M_DIM / 64) * (N_DIM / 64));  // 4096 single-wave blocks
    dim3 block(64);
    linear_wave_tile<<<grid, block, 0, stream>>>(x, w, b, out);
}

// Round 5
// 140.797 us; speedup vs baseline: 1.8591x; 1.4304x over previous
//
#include <hip/hip_runtime.h>
#include <hip/hip_bf16.h>

// Linear layer: out[M,N] = x[M,K] @ W[N,K]^T + b[N], fp32 in/out.
// M=32768, N=512, K=512. bf16 MFMA, fp32 accumulate.
// R5: double-buffered LDS (ONE barrier/iter) + distance-2 register
// prefetch for A (dist-1 for W, issued first so waitcnt stays partial).
// Keeps R2's XCD swizzle (FETCH 133->39MB win) and plain stores
// (nontemporal inflated WRITE 67->89MB).

#define M_DIM 32768
#define N_DIM 512
#define K_DIM 512
#define BK 32
#define LDA 40   // bf16 elems; 80B rows keep b128 alignment

typedef __bf16 bf16x8 __attribute__((ext_vector_type(8)));
typedef __bf16 bf16x4 __attribute__((ext_vector_type(4)));
typedef float floatx4 __attribute__((ext_vector_type(4)));

__global__ __launch_bounds__(256, 3) void linear_dbuf(
    const float* __restrict__ A,    // [M, K]
    const float* __restrict__ W,    // [N, K]
    const float* __restrict__ bias, // [N]
    float* __restrict__ C)          // [M, N]
{
    __shared__ __bf16 sA[2][128 * LDA];
    __shared__ __bf16 sW[2][128 * LDA];

    const int t = threadIdx.x;
    const int bid = blockIdx.x;
    // XCD swizzle: 4 n-tiles of an m-tile land on one XCD adjacent slots.
    const int nT = (bid >> 3) & 3;
    const int mT = (bid & 7) | ((bid >> 5) << 3);
    const int mBlock = mT * 128;
    const int nBlock = nT * 128;

    const int wave = t >> 6;
    const int lane = t & 63;
    const int mW = (wave >> 1) * 64;
    const int nW = (wave & 1) * 64;
    const int kh = lane >> 4;
    const int l16 = lane & 15;

    floatx4 acc[4][4];
#pragma unroll
    for (int i = 0; i < 4; ++i)
#pragma unroll
        for (int j = 0; j < 4; ++j)
            acc[i][j] = (floatx4)0.f;

    // Staging map (as R2): thread t covers rows sRow+{0,32,64,96}, 4 floats
    // at col sCol. Coalesced 128B per 8-lane row-group.
    const int sRow = t >> 3;
    const int sCol = (t & 7) * 4;
    const float* aBase = A + (size_t)(mBlock + sRow) * K_DIM + sCol;
    const float* wBase = W + (size_t)(nBlock + sRow) * K_DIM + sCol;

    // Register prefetch: A has two sets (distance 2), W one set (distance 1).
    floatx4 pa[2][4], pw[4];
#pragma unroll
    for (int i = 0; i < 4; ++i) {
        pa[0][i] = *(const floatx4*)(aBase + (size_t)i * 32 * K_DIM);
        pa[1][i] = *(const floatx4*)(aBase + 32 + (size_t)i * 32 * K_DIM);
        pw[i]    = *(const floatx4*)(wBase + (size_t)i * 32 * K_DIM);
    }

#define STEP(cur, kt)                                                         \
    {                                                                         \
        _Pragma("unroll") for (int i = 0; i < 4; ++i) {                       \
            const int row = sRow + i * 32;                                    \
            bf16x4 ab, wb;                                                    \
            _Pragma("unroll") for (int j = 0; j < 4; ++j) {                   \
                ab[j] = (__bf16)pa[cur][i][j];                                \
                wb[j] = (__bf16)pw[i][j];                                     \
            }                                                                 \
            *(bf16x4*)&sA[cur][row * LDA + sCol] = ab;                        \
            *(bf16x4*)&sW[cur][row * LDA + sCol] = wb;                        \
        }                                                                     \
        __syncthreads(); /* one barrier per iter (double buffer) */           \
        if ((kt) + BK < K_DIM) /* W for next iter: issue FIRST */             \
            _Pragma("unroll") for (int i = 0; i < 4; ++i)                     \
                pw[i] = *(const floatx4*)(wBase + (kt) + BK +                 \
                                          (size_t)i * 32 * K_DIM);            \
        if ((kt) + 2 * BK < K_DIM) /* A for iter+2 into the freed set */      \
            _Pragma("unroll") for (int i = 0; i < 4; ++i)                     \
                pa[cur][i] = *(const floatx4*)(aBase + (kt) + 2 * BK +        \
                                               (size_t)i * 32 * K_DIM);       \
        bf16x8 aF[4], wF[4];                                                  \
        _Pragma("unroll") for (int mi = 0; mi < 4; ++mi)                      \
            aF[mi] = *(const bf16x8*)&sA[cur][(mW + mi * 16 + l16) * LDA +    \
                                             kh * 8];                         \
        _Pragma("unroll") for (int ni = 0; ni < 4; ++ni)                      \
            wF[ni] = *(const bf16x8*)&sW[cur][(nW + ni * 16 + l16) * LDA +    \
                                             kh * 8];                         \
        _Pragma("unroll") for (int mi = 0; mi < 4; ++mi)                      \
            _Pragma("unroll") for (int ni = 0; ni < 4; ++ni)                  \
                acc[mi][ni] = __builtin_amdgcn_mfma_f32_16x16x32_bf16(        \
                    aF[mi], wF[ni], acc[mi][ni], 0, 0, 0);                    \
    }

    for (int it8 = 0; it8 < 8; ++it8) {
        const int kt = it8 * 2 * BK;
        STEP(0, kt);
        STEP(1, kt + BK);
    }
#undef STEP

    // Epilogue: D mapping col = lane&15, row = (lane>>4)*4 + reg (verified).
#pragma unroll
    for (int ni = 0; ni < 4; ++ni) {
        const int gcol = nBlock + nW + ni * 16 + l16;
        const float bv = bias[gcol];
#pragma unroll
        for (int mi = 0; mi < 4; ++mi) {
            const int rowBase = mBlock + mW + mi * 16 + kh * 4;
#pragma unroll
            for (int r = 0; r < 4; ++r)
                C[(size_t)(rowBase + r) * N_DIM + gcol] = acc[mi][ni][r] + bv;
        }
    }
}

extern "C" void kernel_launch(void* const* d_in, const int* in_sizes, int n_in,
                              void* d_out, int out_size, void* d_ws, size_t ws_size,
                              hipStream_t stream) {
    const float* x = (const float*)d_in[0];
    const float* w = (const float*)d_in[1];
    const float* b = (const float*)d_in[2];
    float* out = (float*)d_out;

    dim3 grid((M_DIM / 128) * (N_DIM / 128));  // 1024 blocks, 1D for swizzle
    dim3 block(256);
    linear_dbuf<<<grid, block, 0, stream>>>(x, w, b, out);
}